// Round 15
// baseline (304.430 us; speedup 1.0000x reference)
//
#include <hip/hip_runtime.h>

#define N_NODES 100000
#define N_EDGES 1600000
#define NFEAT 256
#define NHID 64
#define NOUT 16
#define BSIZE 256            // dst-nodes per bucket
#define NBUCK 391            // ceil(N_NODES/256)
#define CHUNK 4096           // edges per chunk
#define NCHUNK 391           // ceil(N_EDGES/4096)
#define MATN (NBUCK * NCHUNK)
#define MSCAN_NB 598         // ceil(MATN/256)

__device__ __forceinline__ unsigned short f2bf(float f) {
  unsigned u = __float_as_uint(f);
  unsigned r = (u + 0x7FFF + ((u >> 16) & 1)) >> 16;  // RNE
  return (unsigned short)r;
}
__device__ __forceinline__ float bf2f(unsigned short b) {
  return __uint_as_float(((unsigned)b) << 16);
}

// ---------------------------------------------------------------------------
// S1: per-chunk bucket histogram -> histMat[bucket*NCHUNK + chunk]
// ---------------------------------------------------------------------------
__global__ __launch_bounds__(256) void histB_kernel(
    const int* __restrict__ dst, int* __restrict__ histMat) {
  __shared__ int hist[NBUCK];
  int t = threadIdx.x;
  int ch = blockIdx.x;
  if (t < NBUCK) hist[t] = 0;
  if (t + 256 < NBUCK) hist[t + 256] = 0;
  __syncthreads();
  int base = ch * CHUNK;
#pragma unroll
  for (int i = 0; i < CHUNK / 256; ++i) {
    int e = base + i * 256 + t;
    if (e < N_EDGES) atomicAdd(&hist[dst[e] >> 8], 1);
  }
  __syncthreads();
  if (t < NBUCK) histMat[t * NCHUNK + ch] = hist[t];
  if (t + 256 < NBUCK) histMat[(t + 256) * NCHUNK + ch] = hist[t + 256];
}

// ---------------------------------------------------------------------------
// S2a: per-256-block scan of histMat -> exclusive-within-block + blockSums
// ---------------------------------------------------------------------------
__global__ __launch_bounds__(256) void mscan1_kernel(
    const int* __restrict__ histMat, int* __restrict__ scanTmp,
    int* __restrict__ blockSums) {
  __shared__ int s[256];
  int t = threadIdx.x;
  int i = blockIdx.x * 256 + t;
  int v = (i < MATN) ? histMat[i] : 0;
  s[t] = v;
  __syncthreads();
  for (int off = 1; off < 256; off <<= 1) {
    int x = (t >= off) ? s[t - off] : 0;
    __syncthreads();
    s[t] += x;
    __syncthreads();
  }
  if (i < MATN) scanTmp[i] = s[t] - v;  // exclusive within block
  if (t == 255) blockSums[blockIdx.x] = s[255];
}

// ---------------------------------------------------------------------------
// S2b: single-block exclusive scan of MSCAN_NB block sums (<=1024)
// ---------------------------------------------------------------------------
__global__ __launch_bounds__(1024) void mscan2_kernel(
    const int* __restrict__ blockSums, int* __restrict__ blockOff) {
  __shared__ int s[1024];
  int t = threadIdx.x;
  int v = (t < MSCAN_NB) ? blockSums[t] : 0;
  s[t] = v;
  __syncthreads();
  for (int off = 1; off < 1024; off <<= 1) {
    int x = (t >= off) ? s[t - off] : 0;
    __syncthreads();
    s[t] += x;
    __syncthreads();
  }
  if (t < MSCAN_NB) blockOff[t] = s[t] - v;  // exclusive
}

// ---------------------------------------------------------------------------
// S2c: mEx[i] = scanTmp[i] + blockOff[block]   (in-place over histMat)
// ---------------------------------------------------------------------------
__global__ __launch_bounds__(256) void mscan3_kernel(
    const int* __restrict__ scanTmp, const int* __restrict__ blockOff,
    int* __restrict__ mEx) {
  int i = blockIdx.x * 256 + threadIdx.x;
  if (i < MATN) mEx[i] = scanTmp[i] + blockOff[blockIdx.x];
}

// ---------------------------------------------------------------------------
// S3: scatter edges into bucket-grouped tmp_vs. No global atomics: each
// (bucket,chunk) range is exclusively owned by this block (from mEx).
// dlow = dst&255 packed into bits 17..24 of x (src < 2^17).
// ---------------------------------------------------------------------------
__global__ __launch_bounds__(256) void scatter2_kernel(
    const int* __restrict__ src, const int* __restrict__ dst,
    const float* __restrict__ edge_val, const int* __restrict__ mEx,
    int2* __restrict__ tmp_vs) {
  __shared__ int cur[NBUCK];
  int t = threadIdx.x;
  int bid = blockIdx.x;
  // bijective XCD swizzle: q=NCHUNK/8, r=NCHUNK%8
  int xcd = bid & 7;
  int q = NCHUNK >> 3, r = NCHUNK & 7;
  int ch = (xcd < r ? xcd * (q + 1) : r * (q + 1) + (xcd - r) * q) + (bid >> 3);
  if (t < NBUCK) cur[t] = mEx[t * NCHUNK + ch];
  if (t + 256 < NBUCK) cur[t + 256] = mEx[(t + 256) * NCHUNK + ch];
  __syncthreads();
  int base = ch * CHUNK;
#pragma unroll
  for (int i = 0; i < CHUNK / 256; ++i) {
    int e = base + i * 256 + t;
    if (e < N_EDGES) {
      int d = dst[e];
      int p = atomicAdd(&cur[d >> 8], 1);  // LDS atomic
      int2 vs;
      vs.x = src[e] | ((d & 255) << 17);
      vs.y = __float_as_int(edge_val[e]);
      tmp_vs[p] = vs;
    }
  }
}

// ---------------------------------------------------------------------------
// S4: within-bucket counting sort. One block per bucket (256 nodes):
// pass1 counts nodes in LDS, local scan -> row_start/counts written here,
// pass2 scatters into exact CSR slots (~32 KB L2-resident window).
// ---------------------------------------------------------------------------
__global__ __launch_bounds__(256) void bucket_sort_kernel(
    const int2* __restrict__ tmp_vs, const int* __restrict__ mEx,
    int2* __restrict__ sorted_vs, int* __restrict__ row_start,
    int* __restrict__ counts) {
  __shared__ int cnt[256], scn[256], cur[256];
  int b = blockIdx.x;
  int t = threadIdx.x;
  int bstart = mEx[b * NCHUNK];
  int bend = (b + 1 < NBUCK) ? mEx[(b + 1) * NCHUNK] : N_EDGES;
  cnt[t] = 0;
  __syncthreads();
  for (int e = bstart + t; e < bend; e += 256)
    atomicAdd(&cnt[((unsigned)tmp_vs[e].x) >> 17], 1);
  __syncthreads();
  scn[t] = cnt[t];
  __syncthreads();
  for (int off = 1; off < 256; off <<= 1) {
    int x = (t >= off) ? scn[t - off] : 0;
    __syncthreads();
    scn[t] += x;
    __syncthreads();
  }
  int excl = scn[t] - cnt[t];
  cur[t] = bstart + excl;
  int node = (b << 8) + t;
  if (node < N_NODES) {
    row_start[node] = bstart + excl;
    counts[node] = cnt[t];
  }
  __syncthreads();
  for (int e = bstart + t; e < bend; e += 256) {
    int2 vs = tmp_vs[e];
    int dlow = ((unsigned)vs.x) >> 17;
    int p = atomicAdd(&cur[dlow], 1);
    int2 o;
    o.x = vs.x & 0x1FFFF;
    o.y = vs.y;
    sorted_vs[p] = o;
  }
}

// ---------------------------------------------------------------------------
// K1: s1t[slice][node][16] = bf16(emb @ W1), slice-tiled so each 16-column
// slice is a contiguous 3.2 MB table (fits one XCD's 4 MB L2).
// Block = 64 rows x 4 waves; wave wq owns slice wq.
// ---------------------------------------------------------------------------
__global__ __launch_bounds__(256) void gemm1_kernel(
    const float* __restrict__ emb, const float* __restrict__ W1,
    unsigned short* __restrict__ s1t) {
  int lane = threadIdx.x & 63;
  int wq = __builtin_amdgcn_readfirstlane(threadIdx.x >> 6);
  int row = blockIdx.x * 64 + lane;
  int rclamp = row < N_NODES ? row : (N_NODES - 1);
  const float* er = emb + (size_t)rclamp * NFEAT;
  const float* w1q = W1 + wq * 16;  // scalar base

  float acc[16];
#pragma unroll
  for (int c = 0; c < 16; ++c) acc[c] = 0.f;

  for (int k0 = 0; k0 < NFEAT; k0 += 16) {
    float eb[16];
#pragma unroll
    for (int q = 0; q < 4; ++q)
      *(float4*)(eb + 4 * q) = *(const float4*)(er + k0 + 4 * q);
#pragma unroll
    for (int j = 0; j < 16; ++j) {
      const float* w = w1q + (size_t)(k0 + j) * NHID;  // lane-invariant
#pragma unroll
      for (int c = 0; c < 16; ++c) acc[c] = fmaf(eb[j], w[c], acc[c]);
    }
  }

  if (row < N_NODES) {
    unsigned short* o = s1t + ((size_t)wq * N_NODES + row) * 16;
    ushort4 pk[4];
#pragma unroll
    for (int g = 0; g < 4; ++g) {
      pk[g].x = f2bf(acc[4 * g + 0]);
      pk[g].y = f2bf(acc[4 * g + 1]);
      pk[g].z = f2bf(acc[4 * g + 2]);
      pk[g].w = f2bf(acc[4 * g + 3]);
    }
    *(ushort4*)(o + 0) = pk[0];
    *(ushort4*)(o + 4) = pk[1];
    *(ushort4*)(o + 8) = pk[2];
    *(ushort4*)(o + 12) = pk[3];
  }
}

// ---------------------------------------------------------------------------
// K2: slice-split SpMM1. Block b: slice = (b&7)&3 so (assuming bid%8 XCD
// round-robin) each XCD gathers from ONE contiguous 3.2 MB slice -> L2-
// resident -> gathers become L2 hits; beyond-L2 traffic drops to the
// compulsory 25.6 MB fill. Wave = (row, slice): lane = slot(0..3) x col(0..15),
// per-lane direct loads (16 lanes share one descriptor -> HW broadcast),
// shfl_xor reduce AFTER loop reconvergence (divergence-safe).
// Writes hraw[node][64] bf16 (raw spmm sum; relu/mask/W2 in gemm2).
// ---------------------------------------------------------------------------
__global__ __launch_bounds__(256) void spmm1_slice_kernel(
    const unsigned short* __restrict__ s1t, const int2* __restrict__ sorted_vs,
    const int* __restrict__ row_start, const int* __restrict__ counts,
    unsigned short* __restrict__ hraw) {
  int b = blockIdx.x;
  int s8 = b & 7;
  int slice = s8 & 3;
  int chunk = (b >> 3) * 2 + (s8 >> 2);  // 0..24999
  int wv = threadIdx.x >> 6;             // 0..3
  int lane = threadIdx.x & 63;
  int slot = lane >> 4;                  // 0..3
  int c = lane & 15;                     // col within slice
  int r = chunk * 4 + wv;                // exact: max 99999
  int beg = row_start[r];
  int end = beg + counts[r];
  const unsigned short* tbl = s1t + (size_t)slice * N_NODES * 16;
  float acc = 0.f;
#pragma unroll 2
  for (int e = beg + slot; e < end; e += 4) {
    int2 vs = sorted_vs[e];
    acc = fmaf(__int_as_float(vs.y), bf2f(tbl[(size_t)vs.x * 16 + c]), acc);
  }
  // reconverged here; reduce across the 4 slots
  acc += __shfl_xor(acc, 16);
  acc += __shfl_xor(acc, 32);
  if (slot == 0) hraw[(size_t)r * NHID + slice * 16 + c] = f2bf(acc);
}

// ---------------------------------------------------------------------------
// K3: gemm2: h = relu(hraw + b1) * mask; support2 = h @ W2.
// Thread per row; W2/b1 lane-invariant -> scalar loads.
// ---------------------------------------------------------------------------
__global__ __launch_bounds__(256) void gemm2_kernel(
    const unsigned short* __restrict__ hraw, const float* __restrict__ b1,
    const float* __restrict__ mask, const float* __restrict__ W2,
    float* __restrict__ support2) {
  int row = blockIdx.x * blockDim.x + threadIdx.x;
  if (row >= N_NODES) return;
  const unsigned short* hr = hraw + (size_t)row * NHID;
  const float* mr = mask + (size_t)row * NHID;
  float h[NHID];
#pragma unroll
  for (int k = 0; k < NHID; k += 4) {
    ushort4 hv = *(const ushort4*)(hr + k);
    float4 m = *(const float4*)(mr + k);
    float4 bb = *(const float4*)(b1 + k);
    h[k + 0] = fmaxf(bf2f(hv.x) + bb.x, 0.f) * m.x;
    h[k + 1] = fmaxf(bf2f(hv.y) + bb.y, 0.f) * m.y;
    h[k + 2] = fmaxf(bf2f(hv.z) + bb.z, 0.f) * m.z;
    h[k + 3] = fmaxf(bf2f(hv.w) + bb.w, 0.f) * m.w;
  }
  float acc[NOUT];
#pragma unroll
  for (int c = 0; c < NOUT; ++c) acc[c] = 0.f;
  for (int k = 0; k < NHID; ++k) {
    float hk = h[k];
    const float* w = W2 + (size_t)k * NOUT;
#pragma unroll
    for (int c = 0; c < NOUT; ++c) acc[c] = fmaf(hk, w[c], acc[c]);
  }
  float* o = support2 + (size_t)row * NOUT;
#pragma unroll
  for (int c = 0; c < NOUT; c += 4) {
    float4 v = {acc[c], acc[c + 1], acc[c + 2], acc[c + 3]};
    *(float4*)(o + c) = v;
  }
}

// ---------------------------------------------------------------------------
// K4: out[row][c] = sum_e val_e * support2[src_e][c] + b2[c]
// 16 lanes per row, 4 rows per wave (round-8 proven version).
// ---------------------------------------------------------------------------
__global__ __launch_bounds__(256) void spmm2_csr_kernel(
    const float* __restrict__ support2, const int2* __restrict__ sorted_vs,
    const int* __restrict__ row_start, const int* __restrict__ counts,
    const float* __restrict__ b2, float* __restrict__ out) {
  int t = blockIdx.x * blockDim.x + threadIdx.x;
  int r = t >> 4;
  int c = t & 15;
  if (r >= N_NODES) return;
  int beg = row_start[r];
  int end = beg + counts[r];
  float acc = 0.f;
#pragma unroll 4
  for (int e = beg; e < end; ++e) {
    int2 vs = sorted_vs[e];
    acc = fmaf(__int_as_float(vs.y), support2[(size_t)vs.x * NOUT + c], acc);
  }
  out[(size_t)r * NOUT + c] = acc + b2[c];
}

extern "C" void kernel_launch(void* const* d_in, const int* in_sizes, int n_in,
                              void* d_out, int out_size, void* d_ws,
                              size_t ws_size, hipStream_t stream) {
  const float* emb = (const float*)d_in[0];
  const float* W1 = (const float*)d_in[1];
  const float* b1 = (const float*)d_in[2];
  const float* W2 = (const float*)d_in[3];
  const float* b2 = (const float*)d_in[4];
  const float* edge_val = (const float*)d_in[5];
  const float* mask = (const float*)d_in[6];
  const int* esrc = (const int*)d_in[7];
  const int* edst = (const int*)d_in[8];

  // workspace layout (4-byte units)
  float* ws = (float*)d_ws;
  int2* tmp_vs = (int2*)ws;                           // [0, 3.2M) 12.8 MB
  unsigned short* s1t = (unsigned short*)ws;          // aliases tmp_vs
                                                      //  (written after sort)
  unsigned short* hraw = (unsigned short*)(ws + 3200000);  // [3.2M, 6.4M)
  int2* sorted_vs = (int2*)(ws + 6400000);            // [6.4M, 9.6M)
  float* support2 = ws + 9600000;                     // [9.6M, 11.2M)
  int* scanTmpM = (int*)support2;                     // aliases support2 (dead
                                                      //  before gemm2 writes)
  int* row_start = (int*)(ws + 11200000);             // 100,000 i
  int* counts = row_start + 100000;                   // 100,000 i
  int* histMat = counts + 100000;                     // 152,881 i (becomes mEx)
  int* mBlockSums = histMat + MATN;                   // 1024 i
  int* mBlockOff = mBlockSums + 1024;                 // 1024 i
  float* out = (float*)d_out;

  // CSR build: chunk-histogram -> matrix scan -> ownership scatter -> sort
  histB_kernel<<<NCHUNK, 256, 0, stream>>>(edst, histMat);
  mscan1_kernel<<<MSCAN_NB, 256, 0, stream>>>(histMat, scanTmpM, mBlockSums);
  mscan2_kernel<<<1, 1024, 0, stream>>>(mBlockSums, mBlockOff);
  mscan3_kernel<<<MSCAN_NB, 256, 0, stream>>>(scanTmpM, mBlockOff, histMat);
  scatter2_kernel<<<NCHUNK, 256, 0, stream>>>(esrc, edst, edge_val, histMat,
                                              tmp_vs);
  bucket_sort_kernel<<<NBUCK, 256, 0, stream>>>(tmp_vs, histMat, sorted_vs,
                                                row_start, counts);

  // dense + sparse pipeline (gemm1 after sort: s1t aliases tmp_vs)
  gemm1_kernel<<<(N_NODES + 63) / 64, 256, 0, stream>>>(emb, W1, s1t);
  spmm1_slice_kernel<<<100000, 256, 0, stream>>>(s1t, sorted_vs, row_start,
                                                 counts, hraw);
  gemm2_kernel<<<(N_NODES + 255) / 256, 256, 0, stream>>>(hraw, b1, mask, W2,
                                                          support2);
  spmm2_csr_kernel<<<(N_NODES * NOUT + 255) / 256, 256, 0, stream>>>(
      support2, sorted_vs, row_start, counts, b2, out);
}

// Round 16
// 216.418 us; speedup vs baseline: 1.4067x; 1.4067x over previous
//
#include <hip/hip_runtime.h>

#define N_NODES 100000
#define N_EDGES 1600000
#define NFEAT 256
#define NHID 64
#define NOUT 16
#define BSIZE 256            // dst-nodes per bucket
#define NBUCK 391            // ceil(N_NODES/256)
#define CHUNK 4096           // edges per chunk
#define NCHUNK 391           // ceil(N_EDGES/4096)
#define MATN (NBUCK * NCHUNK)
#define MSCAN_NB 598         // ceil(MATN/256)

__device__ __forceinline__ unsigned short f2bf(float f) {
  unsigned u = __float_as_uint(f);
  unsigned r = (u + 0x7FFF + ((u >> 16) & 1)) >> 16;  // RNE
  return (unsigned short)r;
}
__device__ __forceinline__ float bf2f(unsigned short b) {
  return __uint_as_float(((unsigned)b) << 16);
}

// ---------------------------------------------------------------------------
// S1: per-chunk bucket histogram -> histMat[bucket*NCHUNK + chunk]
// ---------------------------------------------------------------------------
__global__ __launch_bounds__(256) void histB_kernel(
    const int* __restrict__ dst, int* __restrict__ histMat) {
  __shared__ int hist[NBUCK];
  int t = threadIdx.x;
  int ch = blockIdx.x;
  if (t < NBUCK) hist[t] = 0;
  if (t + 256 < NBUCK) hist[t + 256] = 0;
  __syncthreads();
  int base = ch * CHUNK;
#pragma unroll
  for (int i = 0; i < CHUNK / 256; ++i) {
    int e = base + i * 256 + t;
    if (e < N_EDGES) atomicAdd(&hist[dst[e] >> 8], 1);
  }
  __syncthreads();
  if (t < NBUCK) histMat[t * NCHUNK + ch] = hist[t];
  if (t + 256 < NBUCK) histMat[(t + 256) * NCHUNK + ch] = hist[t + 256];
}

// ---------------------------------------------------------------------------
// S2a: per-256-block scan of histMat -> exclusive-within-block + blockSums
// ---------------------------------------------------------------------------
__global__ __launch_bounds__(256) void mscan1_kernel(
    const int* __restrict__ histMat, int* __restrict__ scanTmp,
    int* __restrict__ blockSums) {
  __shared__ int s[256];
  int t = threadIdx.x;
  int i = blockIdx.x * 256 + t;
  int v = (i < MATN) ? histMat[i] : 0;
  s[t] = v;
  __syncthreads();
  for (int off = 1; off < 256; off <<= 1) {
    int x = (t >= off) ? s[t - off] : 0;
    __syncthreads();
    s[t] += x;
    __syncthreads();
  }
  if (i < MATN) scanTmp[i] = s[t] - v;  // exclusive within block
  if (t == 255) blockSums[blockIdx.x] = s[255];
}

// ---------------------------------------------------------------------------
// S2b: single-block exclusive scan of MSCAN_NB block sums (<=1024)
// ---------------------------------------------------------------------------
__global__ __launch_bounds__(1024) void mscan2_kernel(
    const int* __restrict__ blockSums, int* __restrict__ blockOff) {
  __shared__ int s[1024];
  int t = threadIdx.x;
  int v = (t < MSCAN_NB) ? blockSums[t] : 0;
  s[t] = v;
  __syncthreads();
  for (int off = 1; off < 1024; off <<= 1) {
    int x = (t >= off) ? s[t - off] : 0;
    __syncthreads();
    s[t] += x;
    __syncthreads();
  }
  if (t < MSCAN_NB) blockOff[t] = s[t] - v;  // exclusive
}

// ---------------------------------------------------------------------------
// S2c: mEx[i] = scanTmp[i] + blockOff[block]   (in-place over histMat)
// ---------------------------------------------------------------------------
__global__ __launch_bounds__(256) void mscan3_kernel(
    const int* __restrict__ scanTmp, const int* __restrict__ blockOff,
    int* __restrict__ mEx) {
  int i = blockIdx.x * 256 + threadIdx.x;
  if (i < MATN) mEx[i] = scanTmp[i] + blockOff[blockIdx.x];
}

// ---------------------------------------------------------------------------
// S3: scatter edges into bucket-grouped tmp_vs. No global atomics: each
// (bucket,chunk) range is exclusively owned by this block (from mEx).
// dlow = dst&255 packed into bits 17..24 of x (src < 2^17).
// ---------------------------------------------------------------------------
__global__ __launch_bounds__(256) void scatter2_kernel(
    const int* __restrict__ src, const int* __restrict__ dst,
    const float* __restrict__ edge_val, const int* __restrict__ mEx,
    int2* __restrict__ tmp_vs) {
  __shared__ int cur[NBUCK];
  int t = threadIdx.x;
  int bid = blockIdx.x;
  // bijective XCD swizzle: q=NCHUNK/8, r=NCHUNK%8
  int xcd = bid & 7;
  int q = NCHUNK >> 3, r = NCHUNK & 7;
  int ch = (xcd < r ? xcd * (q + 1) : r * (q + 1) + (xcd - r) * q) + (bid >> 3);
  if (t < NBUCK) cur[t] = mEx[t * NCHUNK + ch];
  if (t + 256 < NBUCK) cur[t + 256] = mEx[(t + 256) * NCHUNK + ch];
  __syncthreads();
  int base = ch * CHUNK;
#pragma unroll
  for (int i = 0; i < CHUNK / 256; ++i) {
    int e = base + i * 256 + t;
    if (e < N_EDGES) {
      int d = dst[e];
      int p = atomicAdd(&cur[d >> 8], 1);  // LDS atomic
      int2 vs;
      vs.x = src[e] | ((d & 255) << 17);
      vs.y = __float_as_int(edge_val[e]);
      tmp_vs[p] = vs;
    }
  }
}

// ---------------------------------------------------------------------------
// S4: within-bucket counting sort. One block per bucket (256 nodes):
// pass1 counts nodes in LDS, local scan -> row_start/counts written here,
// pass2 scatters into exact CSR slots (~32 KB L2-resident window).
// ---------------------------------------------------------------------------
__global__ __launch_bounds__(256) void bucket_sort_kernel(
    const int2* __restrict__ tmp_vs, const int* __restrict__ mEx,
    int2* __restrict__ sorted_vs, int* __restrict__ row_start,
    int* __restrict__ counts) {
  __shared__ int cnt[256], scn[256], cur[256];
  int b = blockIdx.x;
  int t = threadIdx.x;
  int bstart = mEx[b * NCHUNK];
  int bend = (b + 1 < NBUCK) ? mEx[(b + 1) * NCHUNK] : N_EDGES;
  cnt[t] = 0;
  __syncthreads();
  for (int e = bstart + t; e < bend; e += 256)
    atomicAdd(&cnt[((unsigned)tmp_vs[e].x) >> 17], 1);
  __syncthreads();
  scn[t] = cnt[t];
  __syncthreads();
  for (int off = 1; off < 256; off <<= 1) {
    int x = (t >= off) ? scn[t - off] : 0;
    __syncthreads();
    scn[t] += x;
    __syncthreads();
  }
  int excl = scn[t] - cnt[t];
  cur[t] = bstart + excl;
  int node = (b << 8) + t;
  if (node < N_NODES) {
    row_start[node] = bstart + excl;
    counts[node] = cnt[t];
  }
  __syncthreads();
  for (int e = bstart + t; e < bend; e += 256) {
    int2 vs = tmp_vs[e];
    int dlow = ((unsigned)vs.x) >> 17;
    int p = atomicAdd(&cur[dlow], 1);
    int2 o;
    o.x = vs.x & 0x1FFFF;
    o.y = vs.y;
    sorted_vs[p] = o;
  }
}

// ---------------------------------------------------------------------------
// K1: support1 = bf16(emb @ W1)   [100000,256] @ [256,64]
// Block = 64 rows x 4 waves; wave wq owns col-quarter [wq*16, wq*16+16).
// ---------------------------------------------------------------------------
__global__ __launch_bounds__(256) void gemm1_kernel(
    const float* __restrict__ emb, const float* __restrict__ W1,
    unsigned short* __restrict__ out) {
  int lane = threadIdx.x & 63;
  int wq = __builtin_amdgcn_readfirstlane(threadIdx.x >> 6);
  int row = blockIdx.x * 64 + lane;
  int rclamp = row < N_NODES ? row : (N_NODES - 1);
  const float* er = emb + (size_t)rclamp * NFEAT;
  const float* w1q = W1 + wq * 16;  // scalar base

  float acc[16];
#pragma unroll
  for (int c = 0; c < 16; ++c) acc[c] = 0.f;

  for (int k0 = 0; k0 < NFEAT; k0 += 16) {
    float eb[16];
#pragma unroll
    for (int q = 0; q < 4; ++q)
      *(float4*)(eb + 4 * q) = *(const float4*)(er + k0 + 4 * q);
#pragma unroll
    for (int j = 0; j < 16; ++j) {
      const float* w = w1q + (size_t)(k0 + j) * NHID;  // lane-invariant
#pragma unroll
      for (int c = 0; c < 16; ++c) acc[c] = fmaf(eb[j], w[c], acc[c]);
    }
  }

  if (row < N_NODES) {
    unsigned short* o = out + (size_t)row * NHID + wq * 16;
    ushort4 pk[4];
#pragma unroll
    for (int g = 0; g < 4; ++g) {
      pk[g].x = f2bf(acc[4 * g + 0]);
      pk[g].y = f2bf(acc[4 * g + 1]);
      pk[g].z = f2bf(acc[4 * g + 2]);
      pk[g].w = f2bf(acc[4 * g + 3]);
    }
    *(ushort4*)(o + 0) = pk[0];
    *(ushort4*)(o + 4) = pk[1];
    *(ushort4*)(o + 8) = pk[2];
    *(ushort4*)(o + 12) = pk[3];
  }
}

// ---------------------------------------------------------------------------
// K2 (fused): wave per dst row (round-8 proven form, best of 5 variants).
//   acc[lane] = sum_e val_e * bf16 support1[src_e][lane]   (CSR, no atomics)
//   h = relu(acc + b1) * mask
//   support2[row][c] = bf16( sum_k h[k] * W2[k][c] )       (LDS + shfl reduce)
// support2 stored bf16: 3.2 MB table -> fully L2-resident per XCD for spmm2.
// ---------------------------------------------------------------------------
__global__ __launch_bounds__(256) void spmm1_fused_kernel(
    const unsigned short* __restrict__ support1,
    const int2* __restrict__ sorted_vs, const int* __restrict__ row_start,
    const int* __restrict__ counts, const float* __restrict__ b1,
    const float* __restrict__ mask, const float* __restrict__ W2,
    unsigned short* __restrict__ support2) {
  int wave = (blockIdx.x * blockDim.x + threadIdx.x) >> 6;
  int lane = threadIdx.x & 63;
  int wib = threadIdx.x >> 6;
  int r = wave;
  int beg = row_start[r];
  int end = beg + counts[r];
  float acc = 0.f;
#pragma unroll 4
  for (int e = beg; e < end; ++e) {
    int2 vs = sorted_vs[e];
    acc = fmaf(__int_as_float(vs.y),
               bf2f(support1[(size_t)vs.x * NHID + lane]), acc);
  }
  float h = fmaxf(acc + b1[lane], 0.f) * mask[(size_t)r * NHID + lane];

  __shared__ float hsh[4][NHID];
  hsh[wib][lane] = h;
  __syncthreads();
  int q = lane >> 4;   // 0..3 : k-quarter
  int c = lane & 15;   // output col
  float p = 0.f;
#pragma unroll
  for (int i = 0; i < 16; ++i) {
    int k = q * 16 + i;
    p = fmaf(hsh[wib][k], W2[k * NOUT + c], p);
  }
  p += __shfl_xor(p, 16);
  p += __shfl_xor(p, 32);
  if (lane < 16) support2[(size_t)r * NOUT + lane] = f2bf(p);
}

// ---------------------------------------------------------------------------
// K3: out[row][c] = sum_e val_e * bf16 support2[src_e][c] + b2[c]
// 16 lanes per row, 4 rows per wave. support2 table = 3.2 MB (L2-resident).
// ---------------------------------------------------------------------------
__global__ __launch_bounds__(256) void spmm2_csr_kernel(
    const unsigned short* __restrict__ support2,
    const int2* __restrict__ sorted_vs, const int* __restrict__ row_start,
    const int* __restrict__ counts, const float* __restrict__ b2,
    float* __restrict__ out) {
  int t = blockIdx.x * blockDim.x + threadIdx.x;
  int r = t >> 4;
  int c = t & 15;
  if (r >= N_NODES) return;
  int beg = row_start[r];
  int end = beg + counts[r];
  float acc = 0.f;
#pragma unroll 4
  for (int e = beg; e < end; ++e) {
    int2 vs = sorted_vs[e];
    acc = fmaf(__int_as_float(vs.y),
               bf2f(support2[(size_t)vs.x * NOUT + c]), acc);
  }
  out[(size_t)r * NOUT + c] = acc + b2[c];
}

extern "C" void kernel_launch(void* const* d_in, const int* in_sizes, int n_in,
                              void* d_out, int out_size, void* d_ws,
                              size_t ws_size, hipStream_t stream) {
  const float* emb = (const float*)d_in[0];
  const float* W1 = (const float*)d_in[1];
  const float* b1 = (const float*)d_in[2];
  const float* W2 = (const float*)d_in[3];
  const float* b2 = (const float*)d_in[4];
  const float* edge_val = (const float*)d_in[5];
  const float* mask = (const float*)d_in[6];
  const int* esrc = (const int*)d_in[7];
  const int* edst = (const int*)d_in[8];

  // workspace layout (4-byte units)
  float* ws = (float*)d_ws;
  int2* tmp_vs = (int2*)ws;                           // 1.6M int2 (12.8 MB)
  unsigned short* support1 = (unsigned short*)ws;     // aliases tmp_vs
                                                      //  (written after sort)
  int2* sorted_vs = (int2*)(ws + 6400000);            // 1.6M int2
  unsigned short* support2 = (unsigned short*)(ws + 9600000);  // 1.6M bf16
  int* scanTmpM = (int*)(ws + 9600000 + 800000);      // aliases tail of the
                                                      //  support2 region? NO:
                                                      //  placed after 3.2MB
  int* row_start = (int*)(ws + 11200000);             // 100,000 i
  int* counts = row_start + 100000;                   // 100,000 i
  int* histMat = counts + 100000;                     // 152,881 i (becomes mEx)
  int* mBlockSums = histMat + MATN;                   // 1024 i
  int* mBlockOff = mBlockSums + 1024;                 // 1024 i
  float* out = (float*)d_out;

  // CSR build: chunk-histogram -> matrix scan -> ownership scatter -> sort
  histB_kernel<<<NCHUNK, 256, 0, stream>>>(edst, histMat);
  mscan1_kernel<<<MSCAN_NB, 256, 0, stream>>>(histMat, scanTmpM, mBlockSums);
  mscan2_kernel<<<1, 1024, 0, stream>>>(mBlockSums, mBlockOff);
  mscan3_kernel<<<MSCAN_NB, 256, 0, stream>>>(scanTmpM, mBlockOff, histMat);
  scatter2_kernel<<<NCHUNK, 256, 0, stream>>>(esrc, edst, edge_val, histMat,
                                              tmp_vs);
  bucket_sort_kernel<<<NBUCK, 256, 0, stream>>>(tmp_vs, histMat, sorted_vs,
                                                row_start, counts);

  // dense + sparse pipeline (gemm1 after sort: support1 aliases tmp_vs)
  gemm1_kernel<<<(N_NODES + 63) / 64, 256, 0, stream>>>(emb, W1, support1);
  spmm1_fused_kernel<<<N_NODES / 4, 256, 0, stream>>>(
      support1, sorted_vs, row_start, counts, b1, mask, W2, support2);
  spmm2_csr_kernel<<<(N_NODES * NOUT + 255) / 256, 256, 0, stream>>>(
      support2, sorted_vs, row_start, counts, b2, out);
}

// Round 17
// 208.303 us; speedup vs baseline: 1.4615x; 1.0390x over previous
//
#include <hip/hip_runtime.h>

#define N_NODES 100000
#define N_EDGES 1600000
#define NFEAT 256
#define NHID 64
#define NOUT 16
#define BSIZE 256            // dst-nodes per bucket
#define NBUCK 391            // ceil(N_NODES/256)
#define CHUNK 4096           // edges per chunk
#define NCHUNK 391           // ceil(N_EDGES/4096)
#define MATN (NBUCK * NCHUNK)
#define MSCAN_NB 598         // ceil(MATN/256)
#define NG1 1563             // gemm1 blocks: ceil(N_NODES/64)

__device__ __forceinline__ unsigned short f2bf(float f) {
  unsigned u = __float_as_uint(f);
  unsigned r = (u + 0x7FFF + ((u >> 16) & 1)) >> 16;  // RNE
  return (unsigned short)r;
}
__device__ __forceinline__ float bf2f(unsigned short b) {
  return __uint_as_float(((unsigned)b) << 16);
}

// ---------------------------------------------------------------------------
// F1: fused gemm1 || histB. Blocks [0,NG1) compute support1 = bf16(emb@W1)
// (independent of CSR build); blocks [NG1, NG1+NCHUNK) do the per-chunk
// dst-bucket histogram. Overlap hides histB entirely under gemm1's latency.
// ---------------------------------------------------------------------------
__global__ __launch_bounds__(256) void fused_g1h_kernel(
    const float* __restrict__ emb, const float* __restrict__ W1,
    unsigned short* __restrict__ support1, const int* __restrict__ dst,
    int* __restrict__ histMat) {
  __shared__ int hist[NBUCK];
  if (blockIdx.x < NG1) {
    // ---- gemm1 body: 64 rows x 4 waves; wave wq owns 16-col quarter ----
    int lane = threadIdx.x & 63;
    int wq = __builtin_amdgcn_readfirstlane(threadIdx.x >> 6);
    int row = blockIdx.x * 64 + lane;
    int rclamp = row < N_NODES ? row : (N_NODES - 1);
    const float* er = emb + (size_t)rclamp * NFEAT;
    const float* w1q = W1 + wq * 16;  // scalar base

    float acc[16];
#pragma unroll
    for (int c = 0; c < 16; ++c) acc[c] = 0.f;

    for (int k0 = 0; k0 < NFEAT; k0 += 16) {
      float eb[16];
#pragma unroll
      for (int q = 0; q < 4; ++q)
        *(float4*)(eb + 4 * q) = *(const float4*)(er + k0 + 4 * q);
#pragma unroll
      for (int j = 0; j < 16; ++j) {
        const float* w = w1q + (size_t)(k0 + j) * NHID;  // lane-invariant
#pragma unroll
        for (int c = 0; c < 16; ++c) acc[c] = fmaf(eb[j], w[c], acc[c]);
      }
    }

    if (row < N_NODES) {
      unsigned short* o = support1 + (size_t)row * NHID + wq * 16;
      ushort4 pk[4];
#pragma unroll
      for (int g = 0; g < 4; ++g) {
        pk[g].x = f2bf(acc[4 * g + 0]);
        pk[g].y = f2bf(acc[4 * g + 1]);
        pk[g].z = f2bf(acc[4 * g + 2]);
        pk[g].w = f2bf(acc[4 * g + 3]);
      }
      *(ushort4*)(o + 0) = pk[0];
      *(ushort4*)(o + 4) = pk[1];
      *(ushort4*)(o + 8) = pk[2];
      *(ushort4*)(o + 12) = pk[3];
    }
  } else {
    // ---- histB body ----
    int t = threadIdx.x;
    int ch = blockIdx.x - NG1;
    if (t < NBUCK) hist[t] = 0;
    if (t + 256 < NBUCK) hist[t + 256] = 0;
    __syncthreads();
    int base = ch * CHUNK;
#pragma unroll
    for (int i = 0; i < CHUNK / 256; ++i) {
      int e = base + i * 256 + t;
      if (e < N_EDGES) atomicAdd(&hist[dst[e] >> 8], 1);
    }
    __syncthreads();
    if (t < NBUCK) histMat[t * NCHUNK + ch] = hist[t];
    if (t + 256 < NBUCK) histMat[(t + 256) * NCHUNK + ch] = hist[t + 256];
  }
}

// ---------------------------------------------------------------------------
// S2a: per-256-block scan of histMat -> exclusive-within-block + blockSums
// ---------------------------------------------------------------------------
__global__ __launch_bounds__(256) void mscan1_kernel(
    const int* __restrict__ histMat, int* __restrict__ scanTmp,
    int* __restrict__ blockSums) {
  __shared__ int s[256];
  int t = threadIdx.x;
  int i = blockIdx.x * 256 + t;
  int v = (i < MATN) ? histMat[i] : 0;
  s[t] = v;
  __syncthreads();
  for (int off = 1; off < 256; off <<= 1) {
    int x = (t >= off) ? s[t - off] : 0;
    __syncthreads();
    s[t] += x;
    __syncthreads();
  }
  if (i < MATN) scanTmp[i] = s[t] - v;  // exclusive within block
  if (t == 255) blockSums[blockIdx.x] = s[255];
}

// ---------------------------------------------------------------------------
// S2b: single-block exclusive scan of MSCAN_NB block sums (<=1024)
// ---------------------------------------------------------------------------
__global__ __launch_bounds__(1024) void mscan2_kernel(
    const int* __restrict__ blockSums, int* __restrict__ blockOff) {
  __shared__ int s[1024];
  int t = threadIdx.x;
  int v = (t < MSCAN_NB) ? blockSums[t] : 0;
  s[t] = v;
  __syncthreads();
  for (int off = 1; off < 1024; off <<= 1) {
    int x = (t >= off) ? s[t - off] : 0;
    __syncthreads();
    s[t] += x;
    __syncthreads();
  }
  if (t < MSCAN_NB) blockOff[t] = s[t] - v;  // exclusive
}

// mEx computed on the fly by consumers: mEx[i] = scanTmp[i] + blockOff[i>>8]

// ---------------------------------------------------------------------------
// S3: scatter edges into bucket-grouped tmp_vs. No global atomics: each
// (bucket,chunk) range is exclusively owned by this block.
// dlow = dst&255 packed into bits 17..24 of x (src < 2^17).
// ---------------------------------------------------------------------------
__global__ __launch_bounds__(256) void scatter2_kernel(
    const int* __restrict__ src, const int* __restrict__ dst,
    const float* __restrict__ edge_val, const int* __restrict__ scanTmp,
    const int* __restrict__ blockOff, int2* __restrict__ tmp_vs) {
  __shared__ int cur[NBUCK];
  int t = threadIdx.x;
  int bid = blockIdx.x;
  // bijective XCD swizzle: q=NCHUNK/8, r=NCHUNK%8
  int xcd = bid & 7;
  int q = NCHUNK >> 3, r = NCHUNK & 7;
  int ch = (xcd < r ? xcd * (q + 1) : r * (q + 1) + (xcd - r) * q) + (bid >> 3);
  for (int i = t; i < NBUCK; i += 256) {
    int idx = i * NCHUNK + ch;
    cur[i] = scanTmp[idx] + blockOff[idx >> 8];  // mEx on the fly
  }
  __syncthreads();
  int base = ch * CHUNK;
#pragma unroll
  for (int i = 0; i < CHUNK / 256; ++i) {
    int e = base + i * 256 + t;
    if (e < N_EDGES) {
      int d = dst[e];
      int p = atomicAdd(&cur[d >> 8], 1);  // LDS atomic
      int2 vs;
      vs.x = src[e] | ((d & 255) << 17);
      vs.y = __float_as_int(edge_val[e]);
      tmp_vs[p] = vs;
    }
  }
}

// ---------------------------------------------------------------------------
// S4: within-bucket counting sort. One block per bucket (256 nodes):
// pass1 counts nodes in LDS, local scan -> row_start/counts written here,
// pass2 scatters into exact CSR slots (~32 KB L2-resident window).
// ---------------------------------------------------------------------------
__global__ __launch_bounds__(256) void bucket_sort_kernel(
    const int2* __restrict__ tmp_vs, const int* __restrict__ scanTmp,
    const int* __restrict__ blockOff, int2* __restrict__ sorted_vs,
    int* __restrict__ row_start, int* __restrict__ counts) {
  __shared__ int cnt[256], scn[256], cur[256];
  int b = blockIdx.x;
  int t = threadIdx.x;
  int i0 = b * NCHUNK;
  int bstart = scanTmp[i0] + blockOff[i0 >> 8];
  int bend = N_EDGES;
  if (b + 1 < NBUCK) {
    int i1 = (b + 1) * NCHUNK;
    bend = scanTmp[i1] + blockOff[i1 >> 8];
  }
  cnt[t] = 0;
  __syncthreads();
  for (int e = bstart + t; e < bend; e += 256)
    atomicAdd(&cnt[((unsigned)tmp_vs[e].x) >> 17], 1);
  __syncthreads();
  scn[t] = cnt[t];
  __syncthreads();
  for (int off = 1; off < 256; off <<= 1) {
    int x = (t >= off) ? scn[t - off] : 0;
    __syncthreads();
    scn[t] += x;
    __syncthreads();
  }
  int excl = scn[t] - cnt[t];
  cur[t] = bstart + excl;
  int node = (b << 8) + t;
  if (node < N_NODES) {
    row_start[node] = bstart + excl;
    counts[node] = cnt[t];
  }
  __syncthreads();
  for (int e = bstart + t; e < bend; e += 256) {
    int2 vs = tmp_vs[e];
    int dlow = ((unsigned)vs.x) >> 17;
    int p = atomicAdd(&cur[dlow], 1);
    int2 o;
    o.x = vs.x & 0x1FFFF;
    o.y = vs.y;
    sorted_vs[p] = o;
  }
}

// ---------------------------------------------------------------------------
// K2 (fused): wave per dst row (round-8 proven form, best of 5 variants).
//   acc[lane] = sum_e val_e * bf16 support1[src_e][lane]   (CSR, no atomics)
//   h = relu(acc + b1) * mask
//   support2[row][c] = bf16( sum_k h[k] * W2[k][c] )       (LDS + shfl reduce)
// support2 stored bf16: 3.2 MB table -> fully L2-resident per XCD for spmm2.
// ---------------------------------------------------------------------------
__global__ __launch_bounds__(256) void spmm1_fused_kernel(
    const unsigned short* __restrict__ support1,
    const int2* __restrict__ sorted_vs, const int* __restrict__ row_start,
    const int* __restrict__ counts, const float* __restrict__ b1,
    const float* __restrict__ mask, const float* __restrict__ W2,
    unsigned short* __restrict__ support2) {
  int wave = (blockIdx.x * blockDim.x + threadIdx.x) >> 6;
  int lane = threadIdx.x & 63;
  int wib = threadIdx.x >> 6;
  int r = wave;
  int beg = row_start[r];
  int end = beg + counts[r];
  float acc = 0.f;
#pragma unroll 4
  for (int e = beg; e < end; ++e) {
    int2 vs = sorted_vs[e];
    acc = fmaf(__int_as_float(vs.y),
               bf2f(support1[(size_t)vs.x * NHID + lane]), acc);
  }
  float h = fmaxf(acc + b1[lane], 0.f) * mask[(size_t)r * NHID + lane];

  __shared__ float hsh[4][NHID];
  hsh[wib][lane] = h;
  __syncthreads();
  int q = lane >> 4;   // 0..3 : k-quarter
  int c = lane & 15;   // output col
  float p = 0.f;
#pragma unroll
  for (int i = 0; i < 16; ++i) {
    int k = q * 16 + i;
    p = fmaf(hsh[wib][k], W2[k * NOUT + c], p);
  }
  p += __shfl_xor(p, 16);
  p += __shfl_xor(p, 32);
  if (lane < 16) support2[(size_t)r * NOUT + lane] = f2bf(p);
}

// ---------------------------------------------------------------------------
// K3: out[row][c] = sum_e val_e * bf16 support2[src_e][c] + b2[c]
// 16 lanes per row, 4 rows per wave. support2 table = 3.2 MB (L2-resident).
// ---------------------------------------------------------------------------
__global__ __launch_bounds__(256) void spmm2_csr_kernel(
    const unsigned short* __restrict__ support2,
    const int2* __restrict__ sorted_vs, const int* __restrict__ row_start,
    const int* __restrict__ counts, const float* __restrict__ b2,
    float* __restrict__ out) {
  int t = blockIdx.x * blockDim.x + threadIdx.x;
  int r = t >> 4;
  int c = t & 15;
  if (r >= N_NODES) return;
  int beg = row_start[r];
  int end = beg + counts[r];
  float acc = 0.f;
#pragma unroll 4
  for (int e = beg; e < end; ++e) {
    int2 vs = sorted_vs[e];
    acc = fmaf(__int_as_float(vs.y),
               bf2f(support2[(size_t)vs.x * NOUT + c]), acc);
  }
  out[(size_t)r * NOUT + c] = acc + b2[c];
}

extern "C" void kernel_launch(void* const* d_in, const int* in_sizes, int n_in,
                              void* d_out, int out_size, void* d_ws,
                              size_t ws_size, hipStream_t stream) {
  const float* emb = (const float*)d_in[0];
  const float* W1 = (const float*)d_in[1];
  const float* b1 = (const float*)d_in[2];
  const float* W2 = (const float*)d_in[3];
  const float* b2 = (const float*)d_in[4];
  const float* edge_val = (const float*)d_in[5];
  const float* mask = (const float*)d_in[6];
  const int* esrc = (const int*)d_in[7];
  const int* edst = (const int*)d_in[8];

  // workspace layout (4-byte units). support1 NO LONGER aliases tmp_vs:
  // gemm1 now runs concurrently with the CSR build.
  float* ws = (float*)d_ws;
  int2* tmp_vs = (int2*)ws;                           // [0, 3.2M) 12.8 MB
  unsigned short* support1 = (unsigned short*)(ws + 3200000);  // [3.2M, 4.0M)
  int2* sorted_vs = (int2*)(ws + 6400000);            // [6.4M, 9.6M)
  unsigned short* support2 = (unsigned short*)(ws + 9600000);  // [9.6M,10.4M)
  int* scanTmpM = (int*)(ws + 10400000);              // [10.4M, 10.56M)
  int* row_start = (int*)(ws + 11200000);             // 100,000 i
  int* counts = row_start + 100000;                   // 100,000 i
  int* histMat = counts + 100000;                     // 152,881 i
  int* mBlockSums = histMat + MATN;                   // 1024 i
  int* mBlockOff = mBlockSums + 1024;                 // 1024 i
  float* out = (float*)d_out;

  // gemm1 || histB, then scan -> ownership scatter -> in-bucket sort
  fused_g1h_kernel<<<NG1 + NCHUNK, 256, 0, stream>>>(emb, W1, support1, edst,
                                                     histMat);
  mscan1_kernel<<<MSCAN_NB, 256, 0, stream>>>(histMat, scanTmpM, mBlockSums);
  mscan2_kernel<<<1, 1024, 0, stream>>>(mBlockSums, mBlockOff);
  scatter2_kernel<<<NCHUNK, 256, 0, stream>>>(esrc, edst, edge_val, scanTmpM,
                                              mBlockOff, tmp_vs);
  bucket_sort_kernel<<<NBUCK, 256, 0, stream>>>(tmp_vs, scanTmpM, mBlockOff,
                                                sorted_vs, row_start, counts);

  spmm1_fused_kernel<<<N_NODES / 4, 256, 0, stream>>>(
      support1, sorted_vs, row_start, counts, b1, mask, W2, support2);
  spmm2_csr_kernel<<<(N_NODES * NOUT + 255) / 256, 256, 0, stream>>>(
      support2, sorted_vs, row_start, counts, b2, out);
}